// Round 12
// baseline (16871.379 us; speedup 1.0000x reference)
//
#include <hip/hip_runtime.h>
#include <math.h>

// DenseLSTMForecast: B=256, T=1024, H=128, FUTURE=32.
// R10 (8th submit; rounds 5-11 all infra-failed, never measured).
// R10: G=2 gate-register-blocking (256-thread blocks), LDS-traffic halved.
// R9 post-mortem: readlane dot HURT (12.2ms) — v_readlane writes SGPR and
// the dependent VALU read stalls on mandatory wait-states (~8k dead
// cy/step, invisible in VALUBusy). Diagnosis stands though: R7's dot is
// LDS-RETURN-BW bound — 2048 broadcast ds_read_b128/CU/step x ~8.5cy
// ~ 17.4k cy = the measured 19.3k step. Structural cause: thread=gate
// mapping makes every FMA consume one LDS return slot (1:1).
// Fix: each thread owns TWO gate columns (w0[128],w1[128] ~256 regs,
// AGPR overflow ok at 1 wave/SIMD with launch_bounds(256,1)) so each h4
// b128 read feeds 8 FMAs. 256 thr/block, 4 waves/CU: LDS instr/step
// 2048 -> 1024. Also: partial/x loads issued BEFORE the dot and added
// after (R7 chained the dot onto them, exposing L2 latency); 3 barriers
// per step (publish h straight from activation registers); xs/wl LDS
// buffers -> registers. Numerics (sigmoidf_/tanhf, fp32 everywhere)
// unchanged from the verified R7.
// Geometry/rings/flags/prep byte-identical to R7:
// 32 groups x 8 rows, 224 WGs (now 256 thr), 1 block/CU, 7 stages:
//   s0 c1-core   : g1 = xw1*x+b1 + Whh1*h1           -> RH1 ring
//   s1 c2-helper : p2 = xw2*x+b2 + Wih2[:,1:]*h1(t)  -> RP2 ring
//   s2 c2-core   : g2 = p2 + Whh2*h2                 -> RH2 ring
//   s3 c3-helperA: pA = xw3*x+b3 + Wih3[:,1:129]*h1  -> RP3A ring
//   s4 c3-helperB: pB = Wih3[:,129:257]*h2           -> RP3B ring
//   s5 c3-core   : g3 = pA+pB + Whh3*h3              -> RH3 ring
//   s6 head      : o = Wlin.[x,h1,h2,h3]+b           -> RO ring + out

#define TSEQ 1024
#define HH   128
#define TT   1056
#define THR  256

// ---- ws dword offsets (identical to R7) ----
#define PLANES   0                 // 6 planes x [128 k][512 g] fp32
#define SCAL     393216            // xw1,xw2,xw3,bs1,bs2,bs3 (512 each)
#define WLIN     396288            // Wlin[0..384], [385]=b_lin, pad 512
#define XT       396800            // x transposed [1024][256]
#define RH1      658944            // h rings: [16][256][128] fp32
#define RH2      1183232
#define RH3      1707520
#define RO       2231808           // o ring [16][256] fp32
#define RP2      2235904           // partial rings: [8][256][512] fp32
#define RP3A     3284480
#define RP3B     4333056
#define FLAGS    5381632           // 224 x 32-dword lines
#define PREP_TOT 666112            // 658944 + 7168 (flags zeroing)

#define RH1_64 (RH1/2)
#define RH2_64 (RH2/2)
#define RH3_64 (RH3/2)

typedef unsigned long long u64;

__device__ __forceinline__ float sigmoidf_(float v) {
  return 1.0f / (1.0f + expf(-v));
}

__device__ __forceinline__ void wait_c(unsigned* p, unsigned tgt, unsigned& cached) {
  if (cached >= tgt) return;
  unsigned v = __hip_atomic_load(p, __ATOMIC_ACQUIRE, __HIP_MEMORY_SCOPE_AGENT);
  while (v < tgt) {
    __builtin_amdgcn_s_sleep(1);
    v = __hip_atomic_load(p, __ATOMIC_ACQUIRE, __HIP_MEMORY_SCOPE_AGENT);
  }
  cached = v;
}

// ---------------------------------------------------------------------------
__global__ void prep_kernel(const float* __restrict__ x,
                            const float* __restrict__ Wih1, const float* __restrict__ Whh1,
                            const float* __restrict__ bih1, const float* __restrict__ bhh1,
                            const float* __restrict__ Wih2, const float* __restrict__ Whh2,
                            const float* __restrict__ bih2, const float* __restrict__ bhh2,
                            const float* __restrict__ Wih3, const float* __restrict__ Whh3,
                            const float* __restrict__ bih3, const float* __restrict__ bhh3,
                            const float* __restrict__ Wlin, const float* __restrict__ blin,
                            float* __restrict__ ws) {
  int idx = blockIdx.x * 256 + threadIdx.x;
  if (idx < SCAL) {
    int p = idx >> 16;            // plane
    int rem = idx & 65535;
    int k = rem >> 9, g = rem & 511;
    float v;
    switch (p) {
      case 0:  v = Whh1[g * HH + k];         break;
      case 1:  v = Wih2[g * 129 + 1 + k];    break;
      case 2:  v = Whh2[g * HH + k];         break;
      case 3:  v = Wih3[g * 257 + 1 + k];    break;
      case 4:  v = Wih3[g * 257 + 129 + k];  break;
      default: v = Whh3[g * HH + k];         break;
    }
    ws[idx] = v;
  } else if (idx < WLIN) {
    int r = idx - SCAL;
    float v;
    if      (r < 512)  v = Wih1[r];
    else if (r < 1024) v = Wih2[(r - 512) * 129];
    else if (r < 1536) v = Wih3[(r - 1024) * 257];
    else if (r < 2048) v = bih1[r - 1536] + bhh1[r - 1536];
    else if (r < 2560) v = bih2[r - 2048] + bhh2[r - 2048];
    else               v = bih3[r - 2560] + bhh3[r - 2560];
    ws[idx] = v;
  } else if (idx < XT) {
    int j = idx - WLIN;
    ws[idx] = (j < 385) ? Wlin[j] : (j == 385 ? blin[0] : 0.0f);
  } else if (idx < RH1) {
    int j = idx - XT;
    int t = j >> 8, r = j & 255;
    ws[idx] = x[r * TSEQ + t];
  } else if (idx < PREP_TOT) {
    ws[FLAGS + (idx - RH1)] = 0.0f;   // zero flag lines (ws is poisoned)
  }
}

// ---------------------------------------------------------------------------
// G=2 dot: one broadcast h4 read feeds 8 FMAs (2 gates x 4 k).
__device__ __forceinline__ void dot128_g2(const float* __restrict__ w0,
                                          const float* __restrict__ w1,
                                          const float* __restrict__ hbuf,
                                          float acc0[8], float acc1[8]) {
  #pragma unroll
  for (int k4 = 0; k4 < 32; ++k4) {
    const float a0 = w0[4 * k4], a1 = w0[4 * k4 + 1];
    const float a2 = w0[4 * k4 + 2], a3 = w0[4 * k4 + 3];
    const float b0 = w1[4 * k4], b1 = w1[4 * k4 + 1];
    const float b2 = w1[4 * k4 + 2], b3 = w1[4 * k4 + 3];
    #pragma unroll
    for (int a = 0; a < 8; ++a) {
      const float4 h4 = *(const float4*)&hbuf[a * HH + k4 * 4];
      acc0[a] = fmaf(a0, h4.x, fmaf(a1, h4.y, fmaf(a2, h4.z, fmaf(a3, h4.w, acc0[a]))));
      acc1[a] = fmaf(b0, h4.x, fmaf(b1, h4.y, fmaf(b2, h4.z, fmaf(b3, h4.w, acc1[a]))));
    }
  }
}

// ---------------------------------------------------------------------------
// Core stage: gates = dot(Whh,h_own) + [partials or x-term]; act; publish.
// DRH: dword offset of destination h ring.
template <int SSELF, int SWA, int SWB, int NP, int XF, int PB, int PR1, int PR2, int DRH>
__device__ void core_stage(float* __restrict__ wsm, char* SB, int g) {
  const int tid = threadIdx.x;              // [0,256)
  const int r0 = g * 8;
  float* gs   = (float*)SB;                 // [8][512]
  float* hown = (float*)(SB + 16384);       // [8][128]

  unsigned* flagb = (unsigned*)wsm + FLAGS;
  unsigned* Fself = flagb + (size_t)(SSELF * 32 + g) * 32;
  unsigned* Fh    = flagb + (size_t)(6 * 32 + g) * 32;
  unsigned ca = 0, cb = 0, ch = 0;

  float w0[128], w1[128];
  #pragma unroll
  for (int k = 0; k < 128; ++k) {
    w0[k] = wsm[(size_t)PB * 65536 + (size_t)k * 512 + tid];
    w1[k] = wsm[(size_t)PB * 65536 + (size_t)k * 512 + tid + 256];
  }
  const float xw0 = XF ? wsm[SCAL + tid] : 0.f;
  const float xw1 = XF ? wsm[SCAL + tid + 256] : 0.f;
  const float bs0 = XF ? wsm[SCAL + 1536 + tid] : 0.f;
  const float bs1 = XF ? wsm[SCAL + 1536 + tid + 256] : 0.f;

  for (int i = tid; i < 1024; i += THR) hown[i] = 0.f;
  float cst[4] = {0.f, 0.f, 0.f, 0.f};
  __syncthreads();

  for (int t = 0; t < TT; ++t) {
    if (tid == 0) {
      if constexpr (SWA >= 0)
        wait_c(flagb + (size_t)(SWA * 32 + g) * 32, (unsigned)(t + 1), ca);
      if constexpr (SWB >= 0)
        wait_c(flagb + (size_t)(SWB * 32 + g) * 32, (unsigned)(t + 1), cb);
      unsigned ht = (t >= 15) ? (unsigned)(t - 14) : 0u;
      if (XF && t >= TSEQ && (unsigned)t > ht) ht = (unsigned)t;
      if (ht) wait_c(Fh, ht, ch);
    }
    __syncthreads();                 // B1: inputs granted
    const int slot = t & 15;

    // Prefetch cross-stage inputs; latency hides under the dot below.
    float pa0[8], pa1[8], pb0[8], pb1[8], xr[8];
    if constexpr (NP >= 1) {
      #pragma unroll
      for (int a = 0; a < 8; ++a) {
        unsigned u0 = __hip_atomic_load(
            (unsigned*)wsm + PR1 + (size_t)(t & 7) * 131072 + (size_t)(r0 + a) * 512 + tid,
            __ATOMIC_RELAXED, __HIP_MEMORY_SCOPE_AGENT);
        unsigned u1 = __hip_atomic_load(
            (unsigned*)wsm + PR1 + (size_t)(t & 7) * 131072 + (size_t)(r0 + a) * 512 + tid + 256,
            __ATOMIC_RELAXED, __HIP_MEMORY_SCOPE_AGENT);
        pa0[a] = __builtin_bit_cast(float, u0);
        pa1[a] = __builtin_bit_cast(float, u1);
      }
    }
    if constexpr (NP == 2) {
      #pragma unroll
      for (int a = 0; a < 8; ++a) {
        unsigned u0 = __hip_atomic_load(
            (unsigned*)wsm + PR2 + (size_t)(t & 7) * 131072 + (size_t)(r0 + a) * 512 + tid,
            __ATOMIC_RELAXED, __HIP_MEMORY_SCOPE_AGENT);
        unsigned u1 = __hip_atomic_load(
            (unsigned*)wsm + PR2 + (size_t)(t & 7) * 131072 + (size_t)(r0 + a) * 512 + tid + 256,
            __ATOMIC_RELAXED, __HIP_MEMORY_SCOPE_AGENT);
        pb0[a] = __builtin_bit_cast(float, u0);
        pb1[a] = __builtin_bit_cast(float, u1);
      }
    }
    if (XF) {
      #pragma unroll
      for (int a = 0; a < 8; ++a) {
        if (t < TSEQ) {
          xr[a] = wsm[XT + (size_t)t * 256 + r0 + a];
        } else {
          unsigned u = __hip_atomic_load(
              (unsigned*)wsm + RO + (size_t)((t - 1) & 15) * 256 + r0 + a,
              __ATOMIC_RELAXED, __HIP_MEMORY_SCOPE_AGENT);
          xr[a] = __builtin_bit_cast(float, u);
        }
      }
    }

    // Local recurrent dot from zero (no dependency on the loads above).
    float acc0[8] = {0.f, 0.f, 0.f, 0.f, 0.f, 0.f, 0.f, 0.f};
    float acc1[8] = {0.f, 0.f, 0.f, 0.f, 0.f, 0.f, 0.f, 0.f};
    dot128_g2(w0, w1, hown, acc0, acc1);

    #pragma unroll
    for (int a = 0; a < 8; ++a) {
      float add0, add1;
      if constexpr (NP == 0) {
        add0 = fmaf(xw0, xr[a], bs0);
        add1 = fmaf(xw1, xr[a], bs1);
      } else if constexpr (NP == 1) {
        add0 = pa0[a];
        add1 = pa1[a];
      } else {
        add0 = pa0[a] + pb0[a];
        add1 = pa1[a] + pb1[a];
      }
      gs[a * 512 + tid]       = acc0[a] + add0;
      gs[a * 512 + tid + 256] = acc1[a] + add1;
    }
    __syncthreads();                 // B2: gates visible

    // activation: 1024 units / 256 thr = 4 each; publish straight from regs
    {
      const int u = tid & 127;
      const int ab = (tid >> 7) * 4;
      #pragma unroll
      for (int j = 0; j < 4; ++j) {
        const int a = ab + j;
        const float gi = gs[a * 512 + u];
        const float gf = gs[a * 512 + 128 + u];
        const float gg = gs[a * 512 + 256 + u];
        const float go = gs[a * 512 + 384 + u];
        const float c = sigmoidf_(gf) * cst[j] + sigmoidf_(gi) * tanhf(gg);
        cst[j] = c;
        const float h = sigmoidf_(go) * tanhf(c);
        hown[a * HH + u] = h;
        __hip_atomic_store(
            (unsigned*)wsm + DRH + (size_t)slot * 32768 + (size_t)(r0 + a) * 128 + u,
            __builtin_bit_cast(unsigned, h),
            __ATOMIC_RELAXED, __HIP_MEMORY_SCOPE_AGENT);
      }
    }
    __syncthreads();                 // B3: hown visible, stores drained
    if (tid == 0)
      __hip_atomic_fetch_add(Fself, 1u, __ATOMIC_RELAXED, __HIP_MEMORY_SCOPE_AGENT);
  }
}

// ---------------------------------------------------------------------------
// Helper stage: partial = [x-term+bias if XF] + Wpart * h_src(t); publish.
template <int SSELF, int SW, int XF, int PB, int SI, int SRH64, int DRP>
__device__ void helper_stage(float* __restrict__ wsm, char* SB, int g) {
  const int tid = threadIdx.x;
  const int r0 = g * 8;
  float* hin = (float*)SB;                  // [8][128]

  u64* ws64 = (u64*)wsm;
  unsigned* flagb = (unsigned*)wsm + FLAGS;
  unsigned* Fself = flagb + (size_t)(SSELF * 32 + g) * 32;
  unsigned* Fw    = flagb + (size_t)(SW * 32 + g) * 32;
  unsigned* Fh    = flagb + (size_t)(6 * 32 + g) * 32;
  unsigned cw = 0, ch = 0;

  float w0[128], w1[128];
  #pragma unroll
  for (int k = 0; k < 128; ++k) {
    w0[k] = wsm[(size_t)PB * 65536 + (size_t)k * 512 + tid];
    w1[k] = wsm[(size_t)PB * 65536 + (size_t)k * 512 + tid + 256];
  }
  const float xw0 = XF ? wsm[SCAL + SI * 512 + tid] : 0.f;
  const float xw1 = XF ? wsm[SCAL + SI * 512 + tid + 256] : 0.f;
  const float bs0 = XF ? wsm[SCAL + 1536 + SI * 512 + tid] : 0.f;
  const float bs1 = XF ? wsm[SCAL + 1536 + SI * 512 + tid + 256] : 0.f;
  __syncthreads();

  for (int t = 0; t < TT; ++t) {
    if (tid == 0) {
      wait_c(Fw, (unsigned)(t + 1), cw);
      unsigned ht = (t >= 7) ? (unsigned)(t - 6) : 0u;
      if (XF && t >= TSEQ && (unsigned)t > ht) ht = (unsigned)t;
      if (ht) wait_c(Fh, ht, ch);
    }
    __syncthreads();                 // B1
    const int slot = t & 15;

    float xr[8];
    if (XF) {
      #pragma unroll
      for (int a = 0; a < 8; ++a) {
        if (t < TSEQ) {
          xr[a] = wsm[XT + (size_t)t * 256 + r0 + a];
        } else {
          unsigned u = __hip_atomic_load(
              (unsigned*)wsm + RO + (size_t)((t - 1) & 15) * 256 + r0 + a,
              __ATOMIC_RELAXED, __HIP_MEMORY_SCOPE_AGENT);
          xr[a] = __builtin_bit_cast(float, u);
        }
      }
    }
    // stage h_src(t): 512 u64 / 256 thr = 2 each
    #pragma unroll
    for (int i = 0; i < 2; ++i) {
      const int idx = tid + i * 256;
      const int a = idx >> 6, up = idx & 63;
      u64 v = __hip_atomic_load(
          ws64 + SRH64 + (size_t)slot * 16384 + (size_t)(r0 + a) * 64 + up,
          __ATOMIC_RELAXED, __HIP_MEMORY_SCOPE_AGENT);
      *(u64*)&hin[a * HH + up * 2] = v;
    }
    __syncthreads();                 // B2: hin visible

    float acc0[8] = {0.f, 0.f, 0.f, 0.f, 0.f, 0.f, 0.f, 0.f};
    float acc1[8] = {0.f, 0.f, 0.f, 0.f, 0.f, 0.f, 0.f, 0.f};
    dot128_g2(w0, w1, hin, acc0, acc1);

    #pragma unroll
    for (int a = 0; a < 8; ++a) {
      const float v0 = acc0[a] + (XF ? fmaf(xw0, xr[a], bs0) : 0.f);
      const float v1 = acc1[a] + (XF ? fmaf(xw1, xr[a], bs1) : 0.f);
      __hip_atomic_store(
          (unsigned*)wsm + DRP + (size_t)(t & 7) * 131072 + (size_t)(r0 + a) * 512 + tid,
          __builtin_bit_cast(unsigned, v0),
          __ATOMIC_RELAXED, __HIP_MEMORY_SCOPE_AGENT);
      __hip_atomic_store(
          (unsigned*)wsm + DRP + (size_t)(t & 7) * 131072 + (size_t)(r0 + a) * 512 + tid + 256,
          __builtin_bit_cast(unsigned, v1),
          __ATOMIC_RELAXED, __HIP_MEMORY_SCOPE_AGENT);
    }
    __syncthreads();                 // B3: stores drained
    if (tid == 0)
      __hip_atomic_fetch_add(Fself, 1u, __ATOMIC_RELAXED, __HIP_MEMORY_SCOPE_AGENT);
  }
}

// ---------------------------------------------------------------------------
__device__ void head_stage(float* __restrict__ wsm, char* SB, int g,
                           float* __restrict__ out) {
  const int tid = threadIdx.x;
  const int r0 = g * 8;
  float* hin  = (float*)SB;                 // [3][8][128] = 12288 B
  float* obuf = (float*)(SB + 12288);       // [8][32]

  u64* ws64 = (u64*)wsm;
  unsigned* flagb = (unsigned*)wsm + FLAGS;
  unsigned* Fself = flagb + (size_t)(6 * 32 + g) * 32;
  unsigned* Fc3   = flagb + (size_t)(5 * 32 + g) * 32;
  unsigned c3c = 0;

  const int wv = tid >> 6, lane = tid & 63;
  const int row0 = wv, row1 = wv + 4;
  float wlr[6];
  #pragma unroll
  for (int q = 0; q < 6; ++q) wlr[q] = wsm[WLIN + 1 + lane + 64 * q];
  const float wl0 = wsm[WLIN];
  const float blv = wsm[WLIN + 385];
  float xv0 = wsm[XT + r0 + row0];
  float xv1 = wsm[XT + r0 + row1];

  for (int t = 0; t < TT; ++t) {
    if (tid == 0) wait_c(Fc3, (unsigned)(t + 1), c3c);
    __syncthreads();                 // B1
    const int slot = t & 15;

    #pragma unroll
    for (int i = 0; i < 6; ++i) {
      const int idx = tid + i * 256;        // 0..1535
      const int s = idx >> 9, rem = idx & 511;
      const int a = rem >> 6, up = rem & 63;
      const size_t base = (s == 0) ? (size_t)RH1_64 : (s == 1) ? (size_t)RH2_64 : (size_t)RH3_64;
      u64 v = __hip_atomic_load(
          ws64 + base + (size_t)slot * 16384 + (size_t)(r0 + a) * 64 + up,
          __ATOMIC_RELAXED, __HIP_MEMORY_SCOPE_AGENT);
      *(u64*)&hin[(s * 8 + a) * HH + up * 2] = v;
    }
    __syncthreads();                 // B2

    float s0 = 0.f, s1 = 0.f;
    #pragma unroll
    for (int q = 0; q < 6; ++q) {
      const int j = lane + 64 * q;          // 0..383
      const int si = j >> 7, u = j & 127;
      s0 = fmaf(wlr[q], hin[(si * 8 + row0) * HH + u], s0);
      s1 = fmaf(wlr[q], hin[(si * 8 + row1) * HH + u], s1);
    }
    #pragma unroll
    for (int off = 32; off > 0; off >>= 1) {
      s0 += __shfl_down(s0, off, 64);
      s1 += __shfl_down(s1, off, 64);
    }
    if (lane == 0) {
      const float o0 = s0 + fmaf(wl0, xv0, blv);
      const float o1 = s1 + fmaf(wl0, xv1, blv);
      obuf[row0 * 32 + (t & 31)] = o0;
      obuf[row1 * 32 + (t & 31)] = o1;
      __hip_atomic_store((unsigned*)wsm + RO + (size_t)slot * 256 + r0 + row0,
                         __builtin_bit_cast(unsigned, o0),
                         __ATOMIC_RELAXED, __HIP_MEMORY_SCOPE_AGENT);
      __hip_atomic_store((unsigned*)wsm + RO + (size_t)slot * 256 + r0 + row1,
                         __builtin_bit_cast(unsigned, o1),
                         __ATOMIC_RELAXED, __HIP_MEMORY_SCOPE_AGENT);
      xv0 = (t + 1 < TSEQ) ? wsm[XT + (size_t)(t + 1) * 256 + r0 + row0] : o0;
      xv1 = (t + 1 < TSEQ) ? wsm[XT + (size_t)(t + 1) * 256 + r0 + row1] : o1;
    }
    __syncthreads();                 // B3: o-store + obuf drained
    if (tid == 0)
      __hip_atomic_fetch_add(Fself, 1u, __ATOMIC_RELAXED, __HIP_MEMORY_SCOPE_AGENT);

    if ((t & 31) == 31) {
      const int tb = t - 31;
      const int a = tid >> 5, m = tid & 31;
      out[(size_t)(r0 + a) * TT + tb + m] = obuf[a * 32 + m];
    }
  }
}

// ---------------------------------------------------------------------------
__global__ __launch_bounds__(256, 1)
void lstm_kernel(float* __restrict__ wsm, float* __restrict__ out) {
  __shared__ __align__(16) char SB[20480];
  const int s = blockIdx.x >> 5, g = blockIdx.x & 31;
  switch (s) {
    case 0: core_stage<0, -1, -1, 0, 1, 0, 0, 0, RH1>(wsm, SB, g); break;
    case 1: helper_stage<1, 0, 1, 1, 1, RH1_64, RP2>(wsm, SB, g); break;
    case 2: core_stage<2, 1, -1, 1, 0, 2, RP2, 0, RH2>(wsm, SB, g); break;
    case 3: helper_stage<3, 0, 1, 3, 2, RH1_64, RP3A>(wsm, SB, g); break;
    case 4: helper_stage<4, 2, 0, 4, 0, RH2_64, RP3B>(wsm, SB, g); break;
    case 5: core_stage<5, 3, 4, 2, 0, 5, RP3A, RP3B, RH3>(wsm, SB, g); break;
    default: head_stage(wsm, SB, g, out); break;
  }
}

// ---------------------------------------------------------------------------
extern "C" void kernel_launch(void* const* d_in, const int* in_sizes, int n_in,
                              void* d_out, int out_size, void* d_ws, size_t ws_size,
                              hipStream_t stream) {
  const float* x    = (const float*)d_in[0];
  const float* Wih1 = (const float*)d_in[1];
  const float* Whh1 = (const float*)d_in[2];
  const float* bih1 = (const float*)d_in[3];
  const float* bhh1 = (const float*)d_in[4];
  const float* Wih2 = (const float*)d_in[5];
  const float* Whh2 = (const float*)d_in[6];
  const float* bih2 = (const float*)d_in[7];
  const float* bhh2 = (const float*)d_in[8];
  const float* Wih3 = (const float*)d_in[9];
  const float* Whh3 = (const float*)d_in[10];
  const float* bih3 = (const float*)d_in[11];
  const float* bhh3 = (const float*)d_in[12];
  const float* Wlin = (const float*)d_in[13];
  const float* blin = (const float*)d_in[14];
  float* ws  = (float*)d_ws;
  float* out = (float*)d_out;

  prep_kernel<<<PREP_TOT / 256, 256, 0, stream>>>(
      x, Wih1, Whh1, bih1, bhh1, Wih2, Whh2, bih2, bhh2,
      Wih3, Whh3, bih3, bhh3, Wlin, blin, ws);
  lstm_kernel<<<224, THR, 0, stream>>>(ws, out);
}

// Round 14
// 8482.844 us; speedup vs baseline: 1.9889x; 1.9889x over previous
//
#include <hip/hip_runtime.h>
#include <math.h>

// DenseLSTMForecast: B=256, T=1024, H=128, FUTURE=32.
// R11 (2nd submit; round 13 hit GPUAcquisitionTimeout, never measured).
// R11: 4 waves/SIMD via 1024-thread blocks + K-split dot (w[64]/thread).
// R10 post-mortem (measured 16.9ms, VGPR 176, VALU 18.8%, Occ 10.8%):
// halving LDS instr/step DOUBLED time -> LDS-BW theory falsified. Data:
// R7 (2 waves/SIMD) 19.3k cy/step, R10 (1 wave/SIMD) 38.4k, VALU busy-cy
// constant ~7.1k -> PER-WAVE-LATENCY BOUND; wall ~ 1/(waves/SIMD).
// Fix: more co-resident waves WITHOUT register caps (R8's launch_bounds
// cap demoted w[] to AGPRs). A 1024-thr block = 16 waves = 4 waves/SIMD
// guaranteed (block residency, regs <=512/wave always fit). Per-thread
// state shrunk by K-split: thread owns (col, k-half), w[64]; two half-K
// partial dots combined via LDS (gs[8][2][512], +1 read per gate at
// activation; helper combines via ps + one extra barrier).
// Dataflow/rings/flags/prep byte-identical to verified R7/R10 layout:
// 32 groups x 8 rows, 224 WGs x 1024 thr, 1 block/CU, 7 stages:
//   s0 c1-core   : g1 = xw1*x+b1 + Whh1*h1           -> RH1 ring
//   s1 c2-helper : p2 = xw2*x+b2 + Wih2[:,1:]*h1(t)  -> RP2 ring
//   s2 c2-core   : g2 = p2 + Whh2*h2                 -> RH2 ring
//   s3 c3-helperA: pA = xw3*x+b3 + Wih3[:,1:129]*h1  -> RP3A ring
//   s4 c3-helperB: pB = Wih3[:,129:257]*h2           -> RP3B ring
//   s5 c3-core   : g3 = pA+pB + Whh3*h3              -> RH3 ring
//   s6 head      : o = Wlin.[x,h1,h2,h3]+b           -> RO ring + out
// Prediction: step 19.3k -> 10-12k cy (dur ~4.3-5.6ms), Occ ~45%,
// VALUBusy 45-60%, VGPR 110-170. If dur stays ~8ms at 45% occupancy,
// the latency is the inter-stage flag chain -> fuse stages next.

#define TSEQ 1024
#define HH   128
#define TT   1056
#define THR  1024

// ---- ws dword offsets (identical to R7) ----
#define PLANES   0                 // 6 planes x [128 k][512 g] fp32
#define SCAL     393216            // xw1,xw2,xw3,bs1,bs2,bs3 (512 each)
#define WLIN     396288            // Wlin[0..384], [385]=b_lin, pad 512
#define XT       396800            // x transposed [1024][256]
#define RH1      658944            // h rings: [16][256][128] fp32
#define RH2      1183232
#define RH3      1707520
#define RO       2231808           // o ring [16][256] fp32
#define RP2      2235904           // partial rings: [8][256][512] fp32
#define RP3A     3284480
#define RP3B     4333056
#define FLAGS    5381632           // 224 x 32-dword lines
#define PREP_TOT 666112            // 658944 + 7168 (flags zeroing)

#define RH1_64 (RH1/2)
#define RH2_64 (RH2/2)
#define RH3_64 (RH3/2)

typedef unsigned long long u64;

__device__ __forceinline__ float sigmoidf_(float v) {
  return 1.0f / (1.0f + expf(-v));
}

__device__ __forceinline__ void wait_c(unsigned* p, unsigned tgt, unsigned& cached) {
  if (cached >= tgt) return;
  unsigned v = __hip_atomic_load(p, __ATOMIC_ACQUIRE, __HIP_MEMORY_SCOPE_AGENT);
  while (v < tgt) {
    __builtin_amdgcn_s_sleep(1);
    v = __hip_atomic_load(p, __ATOMIC_ACQUIRE, __HIP_MEMORY_SCOPE_AGENT);
  }
  cached = v;
}

// ---------------------------------------------------------------------------
__global__ void prep_kernel(const float* __restrict__ x,
                            const float* __restrict__ Wih1, const float* __restrict__ Whh1,
                            const float* __restrict__ bih1, const float* __restrict__ bhh1,
                            const float* __restrict__ Wih2, const float* __restrict__ Whh2,
                            const float* __restrict__ bih2, const float* __restrict__ bhh2,
                            const float* __restrict__ Wih3, const float* __restrict__ Whh3,
                            const float* __restrict__ bih3, const float* __restrict__ bhh3,
                            const float* __restrict__ Wlin, const float* __restrict__ blin,
                            float* __restrict__ ws) {
  int idx = blockIdx.x * 256 + threadIdx.x;
  if (idx < SCAL) {
    int p = idx >> 16;            // plane
    int rem = idx & 65535;
    int k = rem >> 9, g = rem & 511;
    float v;
    switch (p) {
      case 0:  v = Whh1[g * HH + k];         break;
      case 1:  v = Wih2[g * 129 + 1 + k];    break;
      case 2:  v = Whh2[g * HH + k];         break;
      case 3:  v = Wih3[g * 257 + 1 + k];    break;
      case 4:  v = Wih3[g * 257 + 129 + k];  break;
      default: v = Whh3[g * HH + k];         break;
    }
    ws[idx] = v;
  } else if (idx < WLIN) {
    int r = idx - SCAL;
    float v;
    if      (r < 512)  v = Wih1[r];
    else if (r < 1024) v = Wih2[(r - 512) * 129];
    else if (r < 1536) v = Wih3[(r - 1024) * 257];
    else if (r < 2048) v = bih1[r - 1536] + bhh1[r - 1536];
    else if (r < 2560) v = bih2[r - 2048] + bhh2[r - 2048];
    else               v = bih3[r - 2560] + bhh3[r - 2560];
    ws[idx] = v;
  } else if (idx < XT) {
    int j = idx - WLIN;
    ws[idx] = (j < 385) ? Wlin[j] : (j == 385 ? blin[0] : 0.0f);
  } else if (idx < RH1) {
    int j = idx - XT;
    int t = j >> 8, r = j & 255;
    ws[idx] = x[r * TSEQ + t];
  } else if (idx < PREP_TOT) {
    ws[FLAGS + (idx - RH1)] = 0.0f;   // zero flag lines (ws is poisoned)
  }
}

// ---------------------------------------------------------------------------
// Half-K dot: 64 of 128 k-values, 8 rows. acc[a] = sum_k w[k]*hbuf[a][kh*64+k].
__device__ __forceinline__ void dot64(const float* __restrict__ w,
                                      const float* __restrict__ hb,
                                      float acc[8]) {
  #pragma unroll
  for (int k4 = 0; k4 < 16; ++k4) {
    const float w0 = w[4 * k4], w1 = w[4 * k4 + 1];
    const float w2 = w[4 * k4 + 2], w3 = w[4 * k4 + 3];
    #pragma unroll
    for (int a = 0; a < 8; ++a) {
      const float4 h4 = *(const float4*)&hb[a * HH + k4 * 4];
      acc[a] = fmaf(w0, h4.x, fmaf(w1, h4.y, fmaf(w2, h4.z, fmaf(w3, h4.w, acc[a]))));
    }
  }
}

// ---------------------------------------------------------------------------
// Core stage: gates = Whh*h_own (K-split) + [partials or x-term]; act; publish.
// DRH: dword offset of destination h ring.
template <int SSELF, int SWA, int SWB, int NP, int XF, int PB, int PR1, int PR2, int DRH>
__device__ void core_stage(float* __restrict__ wsm, char* SB, int g) {
  const int tid = threadIdx.x;              // [0,1024)
  const int r0 = g * 8;
  float* gs   = (float*)SB;                 // [8][2][512] = 32768 B
  float* hown = (float*)(SB + 32768);       // [8][128] = 4096 B

  unsigned* flagb = (unsigned*)wsm + FLAGS;
  unsigned* Fself = flagb + (size_t)(SSELF * 32 + g) * 32;
  unsigned* Fh    = flagb + (size_t)(6 * 32 + g) * 32;
  unsigned ca = 0, cb = 0, ch = 0;

  // dot role: (col, k-half)
  const int col = tid & 511, kh = tid >> 9;
  float w[64];
  #pragma unroll
  for (int k = 0; k < 64; ++k)
    w[k] = wsm[(size_t)PB * 65536 + (size_t)(kh * 64 + k) * 512 + col];

  // activation role: unit (row, u); gate cols {u,128+u,256+u,384+u}
  const int row = tid >> 7, u = tid & 127;
  float xw4[4], bs4[4];
  if (XF) {
    #pragma unroll
    for (int q = 0; q < 4; ++q) {
      xw4[q] = wsm[SCAL + q * 128 + u];
      bs4[q] = wsm[SCAL + 1536 + q * 128 + u];
    }
  }

  hown[tid & 1023] = 0.f;                   // 8*128 = 1024 = blockDim
  float cst = 0.f;
  __syncthreads();

  for (int t = 0; t < TT; ++t) {
    if (tid == 0) {
      if constexpr (SWA >= 0)
        wait_c(flagb + (size_t)(SWA * 32 + g) * 32, (unsigned)(t + 1), ca);
      if constexpr (SWB >= 0)
        wait_c(flagb + (size_t)(SWB * 32 + g) * 32, (unsigned)(t + 1), cb);
      unsigned ht = (t >= 15) ? (unsigned)(t - 14) : 0u;
      if (XF && t >= TSEQ && (unsigned)t > ht) ht = (unsigned)t;
      if (ht) wait_c(Fh, ht, ch);
    }
    __syncthreads();                 // B1: inputs granted
    const int slot = t & 15;

    // activation-role prefetch: issue ring/x loads early, consume after B2.
    float pa[4], pb[4], xr;
    if constexpr (NP >= 1) {
      #pragma unroll
      for (int q = 0; q < 4; ++q) {
        unsigned uu = __hip_atomic_load(
            (unsigned*)wsm + PR1 + (size_t)(t & 7) * 131072 +
                (size_t)(r0 + row) * 512 + q * 128 + u,
            __ATOMIC_RELAXED, __HIP_MEMORY_SCOPE_AGENT);
        pa[q] = __builtin_bit_cast(float, uu);
      }
    }
    if constexpr (NP == 2) {
      #pragma unroll
      for (int q = 0; q < 4; ++q) {
        unsigned uu = __hip_atomic_load(
            (unsigned*)wsm + PR2 + (size_t)(t & 7) * 131072 +
                (size_t)(r0 + row) * 512 + q * 128 + u,
            __ATOMIC_RELAXED, __HIP_MEMORY_SCOPE_AGENT);
        pb[q] = __builtin_bit_cast(float, uu);
      }
    }
    if (XF) {
      if (t < TSEQ) {
        xr = wsm[XT + (size_t)t * 256 + r0 + row];
      } else {
        unsigned uu = __hip_atomic_load(
            (unsigned*)wsm + RO + (size_t)((t - 1) & 15) * 256 + r0 + row,
            __ATOMIC_RELAXED, __HIP_MEMORY_SCOPE_AGENT);
        xr = __builtin_bit_cast(float, uu);
      }
    }

    // half-K dot on own h
    float acc[8] = {0.f, 0.f, 0.f, 0.f, 0.f, 0.f, 0.f, 0.f};
    dot64(w, hown + kh * 64, acc);
    #pragma unroll
    for (int a = 0; a < 8; ++a) gs[a * 1024 + kh * 512 + col] = acc[a];
    __syncthreads();                 // B2: half-sums visible

    // activation: 1 unit/thread; combine halves + add-terms; publish h
    {
      float gv[4];
      #pragma unroll
      for (int q = 0; q < 4; ++q) {
        const int c0 = q * 128 + u;
        float add;
        if constexpr (NP == 0)      add = fmaf(xw4[q], xr, bs4[q]);
        else if constexpr (NP == 1) add = pa[q];
        else                        add = pa[q] + pb[q];
        gv[q] = gs[row * 1024 + c0] + gs[row * 1024 + 512 + c0] + add;
      }
      const float c = sigmoidf_(gv[1]) * cst + sigmoidf_(gv[0]) * tanhf(gv[2]);
      cst = c;
      const float h = sigmoidf_(gv[3]) * tanhf(c);
      hown[row * HH + u] = h;
      __hip_atomic_store(
          (unsigned*)wsm + DRH + (size_t)slot * 32768 + (size_t)(r0 + row) * 128 + u,
          __builtin_bit_cast(unsigned, h),
          __ATOMIC_RELAXED, __HIP_MEMORY_SCOPE_AGENT);
    }
    __syncthreads();                 // B3: hown visible, stores drained
    if (tid == 0)
      __hip_atomic_fetch_add(Fself, 1u, __ATOMIC_RELAXED, __HIP_MEMORY_SCOPE_AGENT);
  }
}

// ---------------------------------------------------------------------------
// Helper stage: partial = [x-term+bias if XF] + Wpart * h_src(t) (K-split);
// combine halves via LDS; publish to partial ring.
template <int SSELF, int SW, int XF, int PB, int SI, int SRH64, int DRP>
__device__ void helper_stage(float* __restrict__ wsm, char* SB, int g) {
  const int tid = threadIdx.x;
  const int r0 = g * 8;
  float* ps  = (float*)SB;                  // [8][2][512] = 32768 B
  float* hin = (float*)(SB + 32768);        // [8][128] = 4096 B
  float* xs  = (float*)(SB + 36864);        // [8]

  u64* ws64 = (u64*)wsm;
  unsigned* flagb = (unsigned*)wsm + FLAGS;
  unsigned* Fself = flagb + (size_t)(SSELF * 32 + g) * 32;
  unsigned* Fw    = flagb + (size_t)(SW * 32 + g) * 32;
  unsigned* Fh    = flagb + (size_t)(6 * 32 + g) * 32;
  unsigned cw = 0, ch = 0;

  const int col = tid & 511, kh = tid >> 9;
  float w[64];
  #pragma unroll
  for (int k = 0; k < 64; ++k)
    w[k] = wsm[(size_t)PB * 65536 + (size_t)(kh * 64 + k) * 512 + col];
  const float xwv = XF ? wsm[SCAL + SI * 512 + col] : 0.f;
  const float bsv = XF ? wsm[SCAL + 1536 + SI * 512 + col] : 0.f;
  __syncthreads();

  for (int t = 0; t < TT; ++t) {
    if (tid == 0) {
      wait_c(Fw, (unsigned)(t + 1), cw);
      unsigned ht = (t >= 7) ? (unsigned)(t - 6) : 0u;
      if (XF && t >= TSEQ && (unsigned)t > ht) ht = (unsigned)t;
      if (ht) wait_c(Fh, ht, ch);
    }
    __syncthreads();                 // B1
    const int slot = t & 15;

    if (XF) {
      if (tid < 8) {
        float xv;
        if (t < TSEQ) {
          xv = wsm[XT + (size_t)t * 256 + r0 + tid];
        } else {
          unsigned uu = __hip_atomic_load(
              (unsigned*)wsm + RO + (size_t)((t - 1) & 15) * 256 + r0 + tid,
              __ATOMIC_RELAXED, __HIP_MEMORY_SCOPE_AGENT);
          xv = __builtin_bit_cast(float, uu);
        }
        xs[tid] = xv;
      }
    }
    // stage h_src(t): 512 u64 / first 512 threads
    if (tid < 512) {
      const int a = tid >> 6, up = tid & 63;
      u64 v = __hip_atomic_load(
          ws64 + SRH64 + (size_t)slot * 16384 + (size_t)(r0 + a) * 64 + up,
          __ATOMIC_RELAXED, __HIP_MEMORY_SCOPE_AGENT);
      *(u64*)&hin[a * HH + up * 2] = v;
    }
    __syncthreads();                 // B2: hin (and xs) visible

    float acc[8] = {0.f, 0.f, 0.f, 0.f, 0.f, 0.f, 0.f, 0.f};
    dot64(w, hin + kh * 64, acc);
    #pragma unroll
    for (int a = 0; a < 8; ++a) ps[a * 1024 + kh * 512 + col] = acc[a];
    __syncthreads();                 // B3: half-sums visible

    // combine + publish: 4096 values / 1024 thr = 4 each (same col, rows +2)
    #pragma unroll
    for (int i = 0; i < 4; ++i) {
      const int a = kh + i * 2;             // 0..7
      float v = ps[a * 1024 + col] + ps[a * 1024 + 512 + col];
      if (XF) v += fmaf(xwv, xs[a], bsv);
      __hip_atomic_store(
          (unsigned*)wsm + DRP + (size_t)(t & 7) * 131072 + (size_t)(r0 + a) * 512 + col,
          __builtin_bit_cast(unsigned, v),
          __ATOMIC_RELAXED, __HIP_MEMORY_SCOPE_AGENT);
    }
    __syncthreads();                 // B4: ring stores drained
    if (tid == 0)
      __hip_atomic_fetch_add(Fself, 1u, __ATOMIC_RELAXED, __HIP_MEMORY_SCOPE_AGENT);
  }
}

// ---------------------------------------------------------------------------
__device__ void head_stage(float* __restrict__ wsm, char* SB, int g,
                           float* __restrict__ out) {
  const int tid = threadIdx.x;
  const int r0 = g * 8;
  float* hin  = (float*)SB;                 // [3][8][128] = 12288 B
  float* obuf = (float*)(SB + 12288);       // [8][32]

  u64* ws64 = (u64*)wsm;
  unsigned* flagb = (unsigned*)wsm + FLAGS;
  unsigned* Fself = flagb + (size_t)(6 * 32 + g) * 32;
  unsigned* Fc3   = flagb + (size_t)(5 * 32 + g) * 32;
  unsigned c3c = 0;

  const int row = (tid >> 6) & 7, lane = tid & 63;
  float wlr[6];
  #pragma unroll
  for (int q = 0; q < 6; ++q) wlr[q] = wsm[WLIN + 1 + lane + 64 * q];
  const float wl0 = wsm[WLIN];
  const float blv = wsm[WLIN + 385];
  float xv = wsm[XT + r0 + row];

  for (int t = 0; t < TT; ++t) {
    if (tid == 0) wait_c(Fc3, (unsigned)(t + 1), c3c);
    __syncthreads();                 // B1
    const int slot = t & 15;

    #pragma unroll
    for (int i = 0; i < 2; ++i) {
      const int idx = tid + i * 1024;       // 0..2047, use 0..1535
      if (idx < 1536) {
        const int s = idx >> 9, rem = idx & 511;
        const int a = rem >> 6, up = rem & 63;
        const size_t base = (s == 0) ? (size_t)RH1_64 : (s == 1) ? (size_t)RH2_64 : (size_t)RH3_64;
        u64 v = __hip_atomic_load(
            ws64 + base + (size_t)slot * 16384 + (size_t)(r0 + a) * 64 + up,
            __ATOMIC_RELAXED, __HIP_MEMORY_SCOPE_AGENT);
        *(u64*)&hin[(s * 8 + a) * HH + up * 2] = v;
      }
    }
    __syncthreads();                 // B2

    if (tid < 512) {
      float s = 0.f;
      #pragma unroll
      for (int q = 0; q < 6; ++q) {
        const int j = lane + 64 * q;        // 0..383
        const int si = j >> 7, uu = j & 127;
        s = fmaf(wlr[q], hin[(si * 8 + row) * HH + uu], s);
      }
      #pragma unroll
      for (int off = 32; off > 0; off >>= 1) s += __shfl_down(s, off, 64);
      if (lane == 0) {
        const float o = s + fmaf(wl0, xv, blv);
        obuf[row * 32 + (t & 31)] = o;
        __hip_atomic_store((unsigned*)wsm + RO + (size_t)slot * 256 + r0 + row,
                           __builtin_bit_cast(unsigned, o),
                           __ATOMIC_RELAXED, __HIP_MEMORY_SCOPE_AGENT);
        xv = (t + 1 < TSEQ) ? wsm[XT + (size_t)(t + 1) * 256 + r0 + row] : o;
      }
    }
    __syncthreads();                 // B3: o-store + obuf drained
    if (tid == 0)
      __hip_atomic_fetch_add(Fself, 1u, __ATOMIC_RELAXED, __HIP_MEMORY_SCOPE_AGENT);

    if ((t & 31) == 31) {
      const int tb = t - 31;
      if (tid < 256) {
        const int a = tid >> 5, m = tid & 31;
        out[(size_t)(r0 + a) * TT + tb + m] = obuf[a * 32 + m];
      }
    }
  }
}

// ---------------------------------------------------------------------------
__global__ __launch_bounds__(1024)
void lstm_kernel(float* __restrict__ wsm, float* __restrict__ out) {
  __shared__ __align__(16) char SB[36992];
  const int s = blockIdx.x >> 5, g = blockIdx.x & 31;
  switch (s) {
    case 0: core_stage<0, -1, -1, 0, 1, 0, 0, 0, RH1>(wsm, SB, g); break;
    case 1: helper_stage<1, 0, 1, 1, 1, RH1_64, RP2>(wsm, SB, g); break;
    case 2: core_stage<2, 1, -1, 1, 0, 2, RP2, 0, RH2>(wsm, SB, g); break;
    case 3: helper_stage<3, 0, 1, 3, 2, RH1_64, RP3A>(wsm, SB, g); break;
    case 4: helper_stage<4, 2, 0, 4, 0, RH2_64, RP3B>(wsm, SB, g); break;
    case 5: core_stage<5, 3, 4, 2, 0, 5, RP3A, RP3B, RH3>(wsm, SB, g); break;
    default: head_stage(wsm, SB, g, out); break;
  }
}

// ---------------------------------------------------------------------------
extern "C" void kernel_launch(void* const* d_in, const int* in_sizes, int n_in,
                              void* d_out, int out_size, void* d_ws, size_t ws_size,
                              hipStream_t stream) {
  const float* x    = (const float*)d_in[0];
  const float* Wih1 = (const float*)d_in[1];
  const float* Whh1 = (const float*)d_in[2];
  const float* bih1 = (const float*)d_in[3];
  const float* bhh1 = (const float*)d_in[4];
  const float* Wih2 = (const float*)d_in[5];
  const float* Whh2 = (const float*)d_in[6];
  const float* bih2 = (const float*)d_in[7];
  const float* bhh2 = (const float*)d_in[8];
  const float* Wih3 = (const float*)d_in[9];
  const float* Whh3 = (const float*)d_in[10];
  const float* bih3 = (const float*)d_in[11];
  const float* bhh3 = (const float*)d_in[12];
  const float* Wlin = (const float*)d_in[13];
  const float* blin = (const float*)d_in[14];
  float* ws  = (float*)d_ws;
  float* out = (float*)d_out;

  prep_kernel<<<PREP_TOT / 256, 256, 0, stream>>>(
      x, Wih1, Whh1, bih1, bhh1, Wih2, Whh2, bih2, bhh2,
      Wih3, Whh3, bih3, bhh3, Wlin, blin, ws);
  lstm_kernel<<<224, THR, 0, stream>>>(ws, out);
}